// Round 7
// baseline (193.758 us; speedup 1.0000x reference)
//
#include <hip/hip_runtime.h>
#include <hip/hip_cooperative_groups.h>
namespace cg = cooperative_groups;

#define MT 64      // number of event types M
#define KK 4       // number of kernels K
#define NBF 4096   // scan blocks (fused path): 512 WGs x 8 waves
#define MAXBF 52   // max events/block in fused LDS tiles (N <= 212992)
#define MAXB 64    // old-path tile bound

// ---------- helpers ----------
__device__ __forceinline__ float wredf(float v) {
  #pragma unroll
  for (int off = 32; off > 0; off >>= 1) v += __shfl_xor(v, off, 64);
  return v;
}
__device__ __forceinline__ double wredd(double v) {
  #pragma unroll
  for (int off = 32; off > 0; off >>= 1) v += __shfl_xor(v, off, 64);
  return v;
}
__device__ __forceinline__ float4 f4fma(float4 a, float4 b, float4 c) { // a*b+c
  return make_float4(fmaf(a.x,b.x,c.x), fmaf(a.y,b.y,c.y),
                     fmaf(a.z,b.z,c.z), fmaf(a.w,b.w,c.w));
}
__device__ __forceinline__ float4 f4mul(float4 a, float4 b) {
  return make_float4(a.x*b.x, a.y*b.y, a.z*b.z, a.w*b.w);
}
__device__ __forceinline__ float parse_T(const int* Tp) {
  int v = *Tp;
  if (v >= 1 && v <= 1000000000) return (float)v;
  return __int_as_float(v);
}

// ================= FUSED cooperative kernel =================
__global__ __launch_bounds__(512, 4) void k_fused(
    const float* __restrict__ t, const int* __restrict__ mi,
    const float* __restrict__ alpha, const float* __restrict__ gamma,
    const float* __restrict__ mu, const int* __restrict__ Tp,
    float4* __restrict__ Ag, float4* __restrict__ gdec,
    float4* __restrict__ GPp, float4* __restrict__ Gmd,
    float4* __restrict__ SgG, float4* __restrict__ sdecG,
    float* __restrict__ compP, float* __restrict__ npt,
    float* __restrict__ out, int N, int B)
{
  __shared__ float4 AT4[MT*MT];              // 64 KB: AT4[m*64+n]={gamma_k*alpha[k][m][n]}
  __shared__ float4 d4t[8*MAXBF];            // 6.5 KB: this WG's per-event decay factors
  __shared__ unsigned char miL[8*MAXBF];     // event types (m < 64 fits u8)
  __shared__ float4 cwPool[8*64 + 8];        // cw[512] + cwd[8]; asumS overlays cw
  __shared__ float red[8];
  __shared__ double s3[3][8];
  float4* cw    = cwPool;
  float4* cwd   = cwPool + 8*64;
  float*  asumS = (float*)cwPool;            // 256 floats; dead before cw is written

  const int tid = threadIdx.x, lane = tid & 63, wv = tid >> 6;
  const int bid = blockIdx.x;
  const float g0=gamma[0], g1=gamma[1], g2=gamma[2], g3=gamma[3];

  // ---- stage tables (once for the whole pipeline) ----
  #pragma unroll
  for (int idx = tid; idx < MT*MT; idx += 512) {
    float a0=alpha[idx],         a1=alpha[MT*MT+idx];
    float a2=alpha[2*MT*MT+idx], a3=alpha[3*MT*MT+idx];
    AT4[idx] = make_float4(g0*a0, g1*a1, g2*a2, g3*a3);
  }
  if (tid < MT*KK) {
    const int m = tid >> 2, k = tid & 3;
    const float4* row = (const float4*)(alpha + (size_t)k*MT*MT + m*MT);
    float s = 0.f;
    #pragma unroll
    for (int j = 0; j < MT/4; ++j) { float4 v = row[j]; s += (v.x+v.y)+(v.z+v.w); }
    asumS[(m<<2)+k] = s;
  }
  __syncthreads();

  // ---- Phase A1: event tiles + compensator (one event per thread) ----
  const float T = parse_T(Tp);
  const int s0w = bid * 8 * B;
  const int BPW = 8 * B;
  float comp = 0.f;
  for (int j = tid; j < BPW; j += 512) {
    const int i = s0w + j;
    if (i < N) {
      float ti = t[i];
      float tp = (i > 0) ? t[i-1] : ti;
      float dt = ti - tp;
      d4t[j] = make_float4(__expf(-g0*dt), __expf(-g1*dt),
                           __expf(-g2*dt), __expf(-g3*dt));
      int m = mi[i];
      miL[j] = (unsigned char)m;
      float x = T - ti;
      float4 as = ((const float4*)asumS)[m];
      comp = fmaf(as.x, 1.f-__expf(-g0*x), comp);
      comp = fmaf(as.y, 1.f-__expf(-g1*x), comp);
      comp = fmaf(as.z, 1.f-__expf(-g2*x), comp);
      comp = fmaf(as.w, 1.f-__expf(-g3*x), comp);
    }
  }
  comp = wredf(comp);
  if (lane == 0) red[wv] = comp;
  __syncthreads();                           // tiles done; asum reads done
  if (tid == 0) {
    float c = 0.f;
    #pragma unroll
    for (int j = 0; j < 8; ++j) c += red[j];
    compP[bid] = c;
  }

  // ---- Phase A2: wave-per-block local q-scan (LDS only, no transcendentals) ----
  const int b  = bid*8 + wv;
  const int s0 = b*B, e0 = min(N, s0+B);
  float4 q = make_float4(0.f,0.f,0.f,0.f);
  {
    int j = wv*B;
    #pragma unroll 4
    for (int i = s0; i < e0; ++i, ++j) {
      float4 d = d4t[j];                     // wave-uniform LDS broadcast
      int m = miL[j];                        // wave-uniform
      float4 a = AT4[(m<<6) + lane];         // contiguous 1KB/wave, conflict-free
      q = f4fma(q, d, a);
    }
  }
  float4 df = make_float4(1.f,1.f,1.f,1.f);
  if (lane == 0) {
    int last  = max(e0-1, 0);
    int plast = min(max(s0-1, 0), N-1);
    float dtb = t[last] - t[plast];
    df = make_float4(__expf(-g0*dtb),__expf(-g1*dtb),
                     __expf(-g2*dtb),__expf(-g3*dtb));
  }
  cw[wv*64 + lane] = q;
  if (lane == 0) cwd[wv] = df;
  __syncthreads();

  // ---- Phase A3: intra-octet cross-wave scan; keep Cl/Dc in REGISTERS ----
  float4 c  = make_float4(0.f,0.f,0.f,0.f);
  float4 dp = make_float4(1.f,1.f,1.f,1.f);
  float4 Cl = c, Dc = dp;
  #pragma unroll
  for (int j = 0; j < 8; ++j) {
    if (j == wv) { Cl = c; Dc = dp; }
    float4 d = cwd[j];
    float4 P = cw[j*64 + lane];
    c  = f4fma(c, d, P);
    dp = f4mul(dp, d);
  }
  if (wv == 0) {
    Ag[(size_t)bid*64 + lane] = c;
    if (lane == 0) gdec[bid] = dp;
  }

  cg::this_grid().sync();

  // ---- Phase B: middle scan over octets (WGs 0..15, wave 0; 32 octets each) ----
  if (bid < 16 && wv == 0) {
    float4 mc  = make_float4(0.f,0.f,0.f,0.f);
    float4 mdp = make_float4(1.f,1.f,1.f,1.f);
    const int o0 = bid*32;
    #pragma unroll 8
    for (int j = 0; j < 32; ++j) {
      const int oct = o0 + j;
      GPp[(size_t)oct*64 + lane] = mc;
      if (lane == 0) Gmd[oct] = mdp;
      float4 gd = gdec[oct];
      float4 a  = Ag[(size_t)oct*64 + lane];
      mc  = f4fma(mc, gd, a);
      mdp = f4mul(mdp, gd);
    }
    SgG[(size_t)bid*64 + lane] = mc;
    if (lane == 0) sdecG[bid] = mdp;
  }

  cg::this_grid().sync();

  // ---- Phase C: fold super-carry (redundant, <=15 steps) + replay ----
  const int sup = bid >> 5;
  float4 tc = make_float4(0.f,0.f,0.f,0.f);
  #pragma unroll 4
  for (int s = 0; s < sup; ++s) {
    float4 sd = sdecG[s];
    float4 a  = SgG[(size_t)s*64 + lane];
    tc = f4fma(tc, sd, a);
  }
  {
    float4 gp = GPp[(size_t)bid*64 + lane];
    float4 gm = Gmd[bid];
    q = f4fma(Dc, f4fma(gm, tc, gp), Cl);    // carry into block b
  }
  const float muL = mu[lane];
  float acc = 0.f;
  {
    int j = wv*B;
    #pragma unroll 4
    for (int i = s0; i < e0; ++i, ++j) {
      float4 d = d4t[j];                     // still resident from phase A
      int m = miL[j];
      float4 a = AT4[(m<<6) + lane];
      float s = q.x*d.x; s=fmaf(q.y,d.y,s); s=fmaf(q.z,d.z,s); s=fmaf(q.w,d.w,s);
      acc += (lane == m) ? __log2f(s + muL) : 0.f;
      q = f4fma(q, d, a);
    }
  }
  float nll = wredf(acc);
  if (lane == 0) npt[b] = nll;

  cg::this_grid().sync();

  // ---- Phase D: final deterministic reduction (WG 0) ----
  if (bid == 0) {
    double sc = 0.0, sn = 0.0;
    for (int i = tid; i < 512; i += 512) sc += (double)compP[i];
    for (int i = tid; i < NBF; i += 512) sn += (double)npt[i];
    double sm = (tid < MT) ? (double)mu[tid] : 0.0;
    sc = wredd(sc); sn = wredd(sn); sm = wredd(sm);
    if (lane == 0) { s3[0][wv]=sc; s3[1][wv]=sn; s3[2][wv]=sm; }
    __syncthreads();
    if (tid == 0) {
      double C=0.0, L=0.0, Mm=0.0;
      #pragma unroll
      for (int j = 0; j < 8; ++j) { C+=s3[0][j]; L+=s3[1][j]; Mm+=s3[2][j]; }
      L *= 0.6931471805599453;               // acc was log2
      double Td = (double)parse_T(Tp);
      out[0] = (float)((C + Td*Mm - L) / (double)N);
    }
  }
}

// ================= Fallback path (proven R6 4-kernel pipeline) =================
__global__ __launch_bounds__(512, 4) void k_phase1(
    const float* __restrict__ t, const int* __restrict__ mi,
    const float* __restrict__ alpha, const float* __restrict__ gamma,
    const int* __restrict__ Tp,
    float4* __restrict__ Cl8, float4* __restrict__ Dc8,
    float4* __restrict__ Ag, float4* __restrict__ gdec,
    float* __restrict__ compP, int N, int B)
{
  __shared__ float4 AT4[MT*MT];
  __shared__ float4 asumS[MT];
  __shared__ float red[8];
  __shared__ __align__(16) unsigned char upool[8*MAXB*16 + 8*MAXB*4];
  float4* d4t = (float4*)upool;
  int*    miL = (int*)(upool + 8*MAXB*16);
  float4* cw  = (float4*)upool;
  float4* cwd = (float4*)(upool + 8192);

  const int tid = threadIdx.x, lane = tid & 63, wv = tid >> 6;
  const float g0=gamma[0], g1=gamma[1], g2=gamma[2], g3=gamma[3];

  #pragma unroll
  for (int idx = tid; idx < MT*MT; idx += 512) {
    float a0=alpha[idx],         a1=alpha[MT*MT+idx];
    float a2=alpha[2*MT*MT+idx], a3=alpha[3*MT*MT+idx];
    AT4[idx] = make_float4(g0*a0, g1*a1, g2*a2, g3*a3);
  }
  if (tid < MT*KK) {
    const int m = tid >> 2, k = tid & 3;
    const float4* row = (const float4*)(alpha + (size_t)k*MT*MT + m*MT);
    float s = 0.f;
    #pragma unroll
    for (int j = 0; j < MT/4; ++j) { float4 v = row[j]; s += (v.x+v.y)+(v.z+v.w); }
    ((float*)asumS)[(m<<2)+k] = s;
  }
  __syncthreads();

  const float T = parse_T(Tp);
  const int s0w = (int)blockIdx.x * 8 * B;
  const int BPW = 8 * B;
  float comp = 0.f;
  for (int j = tid; j < BPW; j += 512) {
    const int i = s0w + j;
    if (i < N) {
      float ti = t[i];
      float tp = (i > 0) ? t[i-1] : ti;
      float dt = ti - tp;
      d4t[j] = make_float4(__expf(-g0*dt), __expf(-g1*dt),
                           __expf(-g2*dt), __expf(-g3*dt));
      int m = mi[i];
      miL[j] = m;
      float x = T - ti;
      float4 as = asumS[m];
      comp = fmaf(as.x, 1.f-__expf(-g0*x), comp);
      comp = fmaf(as.y, 1.f-__expf(-g1*x), comp);
      comp = fmaf(as.z, 1.f-__expf(-g2*x), comp);
      comp = fmaf(as.w, 1.f-__expf(-g3*x), comp);
    }
  }
  comp = wredf(comp);
  if (lane == 0) red[wv] = comp;
  __syncthreads();
  if (tid == 0) {
    float c = 0.f;
    #pragma unroll
    for (int j = 0; j < 8; ++j) c += red[j];
    compP[blockIdx.x] = c;
  }

  const int b  = (int)blockIdx.x*8 + wv;
  const int s0 = b*B, e0 = min(N, s0+B);
  float4 q = make_float4(0.f,0.f,0.f,0.f);
  {
    int j = wv*B;
    #pragma unroll 4
    for (int i = s0; i < e0; ++i, ++j) {
      float4 d = d4t[j];
      int m = miL[j];
      float4 a = AT4[(m<<6) + lane];
      q = f4fma(q, d, a);
    }
  }
  float4 df = make_float4(1.f,1.f,1.f,1.f);
  if (lane == 0) {
    int last  = max(e0-1, 0);
    int plast = min(max(s0-1, 0), N-1);
    float dtb = t[last] - t[plast];
    df = make_float4(__expf(-g0*dtb),__expf(-g1*dtb),
                     __expf(-g2*dtb),__expf(-g3*dtb));
  }
  __syncthreads();
  cw[wv*64 + lane] = q;
  if (lane == 0) cwd[wv] = df;
  __syncthreads();

  float4 c  = make_float4(0.f,0.f,0.f,0.f);
  float4 dp = make_float4(1.f,1.f,1.f,1.f);
  float4 Cl = c, Dc = dp;
  #pragma unroll
  for (int j = 0; j < 8; ++j) {
    if (j == wv) { Cl = c; Dc = dp; }
    float4 d = cwd[j];
    float4 P = cw[j*64 + lane];
    c  = f4fma(c, d, P);
    dp = f4mul(dp, d);
  }
  Cl8[(size_t)b*64 + lane] = Cl;
  if (lane == 0) Dc8[b] = Dc;
  if (wv == 0) {
    Ag[(size_t)blockIdx.x*64 + lane] = c;
    if (lane == 0) gdec[blockIdx.x] = dp;
  }
}

__global__ __launch_bounds__(1024) void k_scan2(
    const float4* __restrict__ Ag, const float4* __restrict__ gdec,
    float4* __restrict__ GPp, float4* __restrict__ Gmd, float4* __restrict__ Top,
    int NW)
{
  __shared__ float4 SgL[16*64];
  __shared__ float4 sdec[16];
  const int tid = threadIdx.x, lane = tid & 63, W = tid >> 6;
  float4 c  = make_float4(0.f,0.f,0.f,0.f);
  float4 dp = make_float4(1.f,1.f,1.f,1.f);
  const int base = W*32;
  #pragma unroll 4
  for (int j = 0; j < 32; ++j) {
    const int oct = base + j;
    GPp[(size_t)oct*64 + lane] = c;
    if (lane == 0) Gmd[oct] = dp;
    float4 gd = gdec[oct];
    float4 a  = Ag[(size_t)oct*64 + lane];
    c  = f4fma(c, gd, a);
    dp = f4mul(dp, gd);
  }
  SgL[W*64 + lane] = c;
  if (lane == 0) sdec[W] = dp;
  __syncthreads();
  if (W == 0) {
    float4 tc = make_float4(0.f,0.f,0.f,0.f);
    for (int s = 0; s < NW; ++s) {
      Top[(size_t)s*64 + lane] = tc;
      float4 sd = sdec[s];
      float4 a  = SgL[s*64 + lane];
      tc = f4fma(tc, sd, a);
    }
  }
}

__global__ __launch_bounds__(512, 4) void k_phase3(
    const float* __restrict__ t, const int* __restrict__ mi,
    const float* __restrict__ alpha, const float* __restrict__ gamma,
    const float* __restrict__ mu,
    const float4* __restrict__ Cl8, const float4* __restrict__ Dc8,
    const float4* __restrict__ GPp, const float4* __restrict__ Gmd,
    const float4* __restrict__ Top,
    float* __restrict__ npt, int N, int B)
{
  __shared__ float4 AT4[MT*MT];
  __shared__ float4 d4t[8*MAXB];
  __shared__ int    miL[8*MAXB];
  const int tid = threadIdx.x, lane = tid & 63, wv = tid >> 6;
  const float g0=gamma[0], g1=gamma[1], g2=gamma[2], g3=gamma[3];

  #pragma unroll
  for (int idx = tid; idx < MT*MT; idx += 512) {
    float a0=alpha[idx],         a1=alpha[MT*MT+idx];
    float a2=alpha[2*MT*MT+idx], a3=alpha[3*MT*MT+idx];
    AT4[idx] = make_float4(g0*a0, g1*a1, g2*a2, g3*a3);
  }
  const int s0w = (int)blockIdx.x * 8 * B;
  const int BPW = 8 * B;
  for (int j = tid; j < BPW; j += 512) {
    const int i = s0w + j;
    if (i < N) {
      float ti = t[i];
      float tp = (i > 0) ? t[i-1] : ti;
      float dt = ti - tp;
      d4t[j] = make_float4(__expf(-g0*dt), __expf(-g1*dt),
                           __expf(-g2*dt), __expf(-g3*dt));
      miL[j] = mi[i];
    }
  }
  __syncthreads();

  const int b  = (int)blockIdx.x*8 + wv;
  const int s0 = b*B, e0 = min(N, s0+B);
  const int oct = blockIdx.x, sup = oct >> 5;
  float4 cl = Cl8[(size_t)b*64 + lane];
  float4 gp = GPp[(size_t)oct*64 + lane];
  float4 tp4 = Top[(size_t)sup*64 + lane];
  float4 Dc = Dc8[b];
  float4 gm = Gmd[oct];
  float4 q = f4fma(Dc, f4fma(gm, tp4, gp), cl);

  const float muL = mu[lane];
  float acc = 0.f;
  {
    int j = wv*B;
    #pragma unroll 4
    for (int i = s0; i < e0; ++i, ++j) {
      float4 d = d4t[j];
      int m = miL[j];
      float4 a = AT4[(m<<6) + lane];
      float s = q.x*d.x; s=fmaf(q.y,d.y,s); s=fmaf(q.z,d.z,s); s=fmaf(q.w,d.w,s);
      acc += (lane == m) ? __log2f(s + muL) : 0.f;
      q = f4fma(q, d, a);
    }
  }
  float nll = wredf(acc);
  if (lane == 0) npt[b] = nll;
}

__global__ __launch_bounds__(512) void k_final(
    const float* __restrict__ mu, const int* __restrict__ Tp,
    const float* __restrict__ compP, int nc,
    const float* __restrict__ npt, int NB,
    float* __restrict__ out, int N)
{
  const int tid = threadIdx.x;
  double sc = 0.0, sn = 0.0;
  for (int i = tid; i < nc; i += 512) sc += (double)compP[i];
  for (int i = tid; i < NB; i += 512) sn += (double)npt[i];
  double sm = (tid < MT) ? (double)mu[tid] : 0.0;
  sc = wredd(sc); sn = wredd(sn); sm = wredd(sm);
  __shared__ double s3[3][8];
  const int wv = tid >> 6, lane = tid & 63;
  if (lane == 0) { s3[0][wv]=sc; s3[1][wv]=sn; s3[2][wv]=sm; }
  __syncthreads();
  if (tid == 0) {
    double C=0.0, L=0.0, Mm=0.0;
    #pragma unroll
    for (int j = 0; j < 8; ++j) { C+=s3[0][j]; L+=s3[1][j]; Mm+=s3[2][j]; }
    L *= 0.6931471805599453;
    double T = (double)parse_T(Tp);
    out[0] = (float)((C + T*Mm - L) / (double)N);
  }
}

extern "C" void kernel_launch(void* const* d_in, const int* in_sizes, int n_in,
                              void* d_out, int out_size, void* d_ws, size_t ws_size,
                              hipStream_t stream)
{
  const float* mu    = (const float*)d_in[0];
  const float* alpha = (const float*)d_in[1];   // (K, M, M)
  const float* gamma = (const float*)d_in[2];   // (K,)
  const float* t     = (const float*)d_in[3];   // (N,)
  const int*   mi    = (const int*)d_in[4];     // (N,) int32
  const int*   Tp    = (const int*)d_in[5];     // scalar
  const int N = in_sizes[3];
  float* outp = (float*)d_out;

  // ---- fused path layout ----
  const int Bf = (N + NBF - 1) / NBF;           // 49 at N=200k
  const int NOG = NBF / 8;                      // 512 WGs
  float* p = (float*)d_ws;
  float4* Ag    = (float4*)p; p += (size_t)NOG*256;
  float4* GPp   = (float4*)p; p += (size_t)NOG*256;
  float4* SgG   = (float4*)p; p += (size_t)16*256;
  float4* gdec  = (float4*)p; p += (size_t)NOG*4;
  float4* Gmd   = (float4*)p; p += (size_t)NOG*4;
  float4* sdecG = (float4*)p; p += (size_t)16*4;
  float*  compP = p;          p += NOG;
  float*  npt   = p;          p += NBF;
  // old-path extra buffers (disjoint region after fused ones)
  float4* Cl8   = (float4*)p; p += (size_t)NBF*256;
  float4* Dc8   = (float4*)p; p += (size_t)NBF*4;
  float4* Top   = (float4*)p; p += (size_t)16*256;

  bool launched = false;
  if (Bf <= MAXBF) {
    int Nv = N, Bv = Bf;
    void* args[] = { (void*)&t, (void*)&mi, (void*)&alpha, (void*)&gamma,
                     (void*)&mu, (void*)&Tp, (void*)&Ag, (void*)&gdec,
                     (void*)&GPp, (void*)&Gmd, (void*)&SgG, (void*)&sdecG,
                     (void*)&compP, (void*)&npt, (void*)&outp,
                     (void*)&Nv, (void*)&Bv };
    hipError_t e = hipLaunchCooperativeKernel((const void*)k_fused,
                                              dim3(NOG), dim3(512),
                                              args, 0, stream);
    if (e == hipSuccess) launched = true;
    else (void)hipGetLastError();             // clear sticky error, fall back
  }

  if (!launched) {
    const int NB = 4096;
    const int B  = (N + NB - 1) / NB;
    const int NOG2 = NB / 8;
    const int NW = NOG2 / 32;
    k_phase1<<<NOG2, 512,   0, stream>>>(t, mi, alpha, gamma, Tp, Cl8, Dc8, Ag,
                                         gdec, compP, N, B);
    k_scan2 <<<1,    NW*64, 0, stream>>>(Ag, gdec, GPp, Gmd, Top, NW);
    k_phase3<<<NOG2, 512,   0, stream>>>(t, mi, alpha, gamma, mu, Cl8, Dc8, GPp,
                                         Gmd, Top, npt, N, B);
    k_final <<<1,    512,   0, stream>>>(mu, Tp, compP, NOG2, npt, NB, outp, N);
  }
}

// Round 8
// 37.640 us; speedup vs baseline: 5.1477x; 5.1477x over previous
//
#include <hip/hip_runtime.h>

#define MT 64     // number of event types M
#define KK 4      // number of kernels K
#define NBK 4096  // scan blocks (512 WGs x 8 waves)
#define MAXB 49   // events/block per LDS chunk (N <= 200704 in one chunk; larger N loops)

// ---------- helpers ----------
__device__ __forceinline__ float wredf(float v) {
  #pragma unroll
  for (int off = 32; off > 0; off >>= 1) v += __shfl_xor(v, off, 64);
  return v;
}
__device__ __forceinline__ double wredd(double v) {
  #pragma unroll
  for (int off = 32; off > 0; off >>= 1) v += __shfl_xor(v, off, 64);
  return v;
}
__device__ __forceinline__ float4 f4fma(float4 a, float4 b, float4 c) { // a*b+c
  return make_float4(fmaf(a.x,b.x,c.x), fmaf(a.y,b.y,c.y),
                     fmaf(a.z,b.z,c.z), fmaf(a.w,b.w,c.w));
}
__device__ __forceinline__ float4 f4mul(float4 a, float4 b) {
  return make_float4(a.x*b.x, a.y*b.y, a.z*b.z, a.w*b.w);
}
__device__ __forceinline__ float parse_T(const int* Tp) {
  int v = *Tp;
  if (v >= 1 && v <= 1000000000) return (float)v;
  return __int_as_float(v);
}

// ---------- K1: single serial pass ----------
// Per WG (octet = 8 blocks): stage AT4; parallel fill of d4/mi tiles + cd4G (direct
// exp from block ref) + compensator; wave-per-block serial q-scan emitting per-event
// LOCAL intensity s_loc (masked LDS store); intra-octet cross-wave scan -> Cl8/Dc8
// (carry within octet) + Ag/gdec (octet aggregate / decay product).
__global__ __launch_bounds__(512, 4) void k_phase1(
    const float* __restrict__ t, const int* __restrict__ mi,
    const float* __restrict__ alpha, const float* __restrict__ gamma,
    const int* __restrict__ Tp,
    float4* __restrict__ cd4G, float* __restrict__ slG,
    float4* __restrict__ Cl8, float4* __restrict__ Dc8,
    float4* __restrict__ Ag, float4* __restrict__ gdec,
    float* __restrict__ compP, int N, int B)
{
  __shared__ float4 AT4[MT*MT];                       // 64 KB
  __shared__ __align__(16) unsigned char pool[8320];  // d4t+miL (serial) / cw+cwd (scan)
  __shared__ float sL[8*MAXB];                        // per-event local intensity
  __shared__ float4 asumS[MT];
  __shared__ float red[8];
  float4*        d4t = (float4*)pool;                 // [8*MAXB] 6272 B
  unsigned char* miL = pool + 8*MAXB*16;              // [8*MAXB] 392 B
  float4*        cw  = (float4*)pool;                 // [512] post-serial overlay
  float4*        cwd = (float4*)(pool + 8192);        // [8]

  const int tid = threadIdx.x, lane = tid & 63, wv = tid >> 6;
  const float g0=gamma[0], g1=gamma[1], g2=gamma[2], g3=gamma[3];

  #pragma unroll
  for (int idx = tid; idx < MT*MT; idx += 512) {
    float a0=alpha[idx],         a1=alpha[MT*MT+idx];
    float a2=alpha[2*MT*MT+idx], a3=alpha[3*MT*MT+idx];
    AT4[idx] = make_float4(g0*a0, g1*a1, g2*a2, g3*a3);
  }
  if (tid < MT*KK) {
    const int m = tid >> 2, k = tid & 3;
    const float4* row = (const float4*)(alpha + (size_t)k*MT*MT + m*MT);
    float s = 0.f;
    #pragma unroll
    for (int j = 0; j < MT/4; ++j) { float4 v = row[j]; s += (v.x+v.y)+(v.z+v.w); }
    ((float*)asumS)[(m<<2)+k] = s;
  }
  __syncthreads();

  const float T = parse_T(Tp);
  const int s0w = (int)blockIdx.x * 8 * B;
  const int b  = (int)blockIdx.x*8 + wv;
  const int s0 = b*B, e0 = min(N, s0+B);
  float4 q = make_float4(0.f,0.f,0.f,0.f);
  float comp = 0.f;
  const int nch = (B + MAXB - 1) / MAXB;              // 1 for N<=200704

  for (int ch = 0; ch < nch; ++ch) {
    const int c0 = ch*MAXB;
    const int cb = min(B - c0, MAXB);
    const int tot = 8*cb;
    // ---- parallel fill: d4/mi tiles, cd4G (block-ref decay), compensator ----
    for (int jj = tid; jj < tot; jj += 512) {
      int w = jj / cb, lo = jj - w*cb;
      int i = s0w + w*B + c0 + lo;
      if (i < N) {
        float ti = t[i];
        float tp = (i > 0) ? t[i-1] : ti;
        float dt = ti - tp;
        d4t[jj] = make_float4(__expf(-g0*dt), __expf(-g1*dt),
                              __expf(-g2*dt), __expf(-g3*dt));
        int m = mi[i];
        miL[jj] = (unsigned char)m;
        int refi = s0w + w*B - 1;                     // block ref = t[block_start-1]
        float tr = (refi >= 0) ? t[refi] : t[0];
        float x = ti - tr;
        cd4G[i] = make_float4(__expf(-g0*x), __expf(-g1*x),
                              __expf(-g2*x), __expf(-g3*x));
        float y = T - ti;
        float4 as = asumS[m];
        comp = fmaf(as.x, 1.f-__expf(-g0*y), comp);
        comp = fmaf(as.y, 1.f-__expf(-g1*y), comp);
        comp = fmaf(as.z, 1.f-__expf(-g2*y), comp);
        comp = fmaf(as.w, 1.f-__expf(-g3*y), comp);
      }
    }
    __syncthreads();
    // ---- wave-per-block serial scan (LDS only; no transcendentals) ----
    const int iend = min(cb, e0 - s0 - c0);           // may be <= 0
    int j = wv*cb;
    #pragma unroll 4
    for (int ii = 0; ii < iend; ++ii, ++j) {
      float4 d = d4t[j];                              // wave-uniform broadcast
      int m = miL[j];                                 // wave-uniform
      float4 a = AT4[(m<<6) + lane];                  // 1KB/wave, conflict-free
      float s = q.x*d.x; s=fmaf(q.y,d.y,s); s=fmaf(q.z,d.z,s); s=fmaf(q.w,d.w,s);
      if (lane == m) sL[j] = s;                       // local intensity at event
      q = f4fma(q, d, a);
    }
    __syncthreads();
    // ---- copy s_loc to global (coalesced) ----
    for (int jj = tid; jj < tot; jj += 512) {
      int w = jj / cb, lo = jj - w*cb;
      int i = s0w + w*B + c0 + lo;
      if (i < N) slG[i] = sL[jj];
    }
    __syncthreads();                                  // before next fill / cw overlay
  }

  // ---- compensator partial ----
  comp = wredf(comp);
  if (lane == 0) red[wv] = comp;

  // ---- block decay factor (direct exp over whole block span) ----
  float4 df = make_float4(1.f,1.f,1.f,1.f);
  if (lane == 0) {
    int last  = max(e0-1, 0);
    int plast = min(max(s0-1, 0), N-1);
    float dtb = t[last] - t[plast];
    df = make_float4(__expf(-g0*dtb),__expf(-g1*dtb),
                     __expf(-g2*dtb),__expf(-g3*dtb));
  }
  cw[wv*64 + lane] = q;                               // overlays d4t/miL (dead now)
  if (lane == 0) cwd[wv] = df;
  __syncthreads();

  // ---- intra-octet cross-wave scan ----
  float4 c  = make_float4(0.f,0.f,0.f,0.f);
  float4 dp = make_float4(1.f,1.f,1.f,1.f);
  float4 Cl = c, Dc = dp;
  #pragma unroll
  for (int jo = 0; jo < 8; ++jo) {
    if (jo == wv) { Cl = c; Dc = dp; }
    float4 d = cwd[jo];
    float4 P = cw[jo*64 + lane];
    c  = f4fma(c, d, P);
    dp = f4mul(dp, d);
  }
  Cl8[(size_t)b*64 + lane] = Cl;
  if (lane == 0) Dc8[b] = Dc;
  if (wv == 0) {
    Ag[(size_t)blockIdx.x*64 + lane] = c;
    if (lane == 0) gdec[blockIdx.x] = dp;
    if (lane == 0) {
      float cc = 0.f;
      #pragma unroll
      for (int jr = 0; jr < 8; ++jr) cc += red[jr];
      compP[blockIdx.x] = cc;
    }
  }
}

// ---------- K2: supergroup aggregates (16 independent waves, 16 CUs) ----------
__global__ __launch_bounds__(64) void k_scan2(
    const float4* __restrict__ Ag, const float4* __restrict__ gdec,
    float4* __restrict__ SgG, float4* __restrict__ sdecG)
{
  const int lane = threadIdx.x;
  const int s = blockIdx.x;
  float4 c  = make_float4(0.f,0.f,0.f,0.f);
  float4 dp = make_float4(1.f,1.f,1.f,1.f);
  #pragma unroll 8
  for (int j = 0; j < 32; ++j) {
    const int o = s*32 + j;
    float4 gd = gdec[o];
    float4 a  = Ag[(size_t)o*64 + lane];
    c  = f4fma(c, gd, a);
    dp = f4mul(dp, gd);
  }
  SgG[(size_t)s*64 + lane] = c;
  if (lane == 0) sdecG[s] = dp;
}

// ---------- K3: fully parallel per-event intensity (no serial replay) ----------
// lam_i = mu[m] + s_loc[i] + dot(C4[b][m], cd4[i]),
// C4[b] = Cl8[b] + Dc8[b]*(gp_oct + gd_oct*Top_sup). Per-WG prologue folds
// gp/gd (<=31 steps) and Top (<=15 steps) into LDS.
__global__ __launch_bounds__(512, 4) void k_lam(
    const int* __restrict__ mi, const float* __restrict__ mu,
    const float4* __restrict__ cd4G, const float* __restrict__ slG,
    const float4* __restrict__ Cl8, const float4* __restrict__ Dc8,
    const float4* __restrict__ Ag, const float4* __restrict__ gdec,
    const float4* __restrict__ SgG, const float4* __restrict__ sdecG,
    float* __restrict__ npt, int N, int B)
{
  __shared__ float4 TopL[64];
  __shared__ float4 gpL[64];
  __shared__ float4 gdLs;
  __shared__ float red[8];
  const int tid = threadIdx.x, lane = tid & 63, wv = tid >> 6;
  const int oct = blockIdx.x;
  const int sup = oct >> 5;

  if (wv == 0) {                       // Top fold: carry into supergroup
    float4 tc = make_float4(0.f,0.f,0.f,0.f);
    for (int s = 0; s < sup; ++s)
      tc = f4fma(tc, sdecG[s], SgG[(size_t)s*64 + lane]);
    TopL[lane] = tc;
  } else if (wv == 1) {                // gp fold: carry into octet within supergroup
    float4 gp = make_float4(0.f,0.f,0.f,0.f);
    float4 gd = make_float4(1.f,1.f,1.f,1.f);
    const int o0 = sup << 5;
    for (int o = o0; o < oct; ++o) {
      gp = f4fma(gp, gdec[o], Ag[(size_t)o*64 + lane]);
      gd = f4mul(gd, gdec[o]);
    }
    gpL[lane] = gp;
    if (lane == 0) gdLs = gd;
  }
  __syncthreads();

  const int BPW = 8*B;
  const int i = oct*BPW + tid;
  float v = 0.f;
  if (tid < BPW && i < N) {
    int m = mi[i];
    float4 cd = cd4G[i];
    float sl = slG[i];
    int bl = tid / B;
    int b = oct*8 + bl;
    float4 coct = f4fma(gdLs, TopL[m], gpL[m]);       // carry into octet, at octet ref
    float4 C = f4fma(Dc8[b], coct, Cl8[(size_t)b*64 + m]);  // carry into block at block ref
    float lam = mu[m] + sl + (C.x*cd.x + C.y*cd.y + C.z*cd.z + C.w*cd.w);
    v = __log2f(lam);
  }
  v = wredf(v);
  if (lane == 0) red[wv] = v;
  __syncthreads();
  if (tid == 0) {
    float s = 0.f;
    #pragma unroll
    for (int j = 0; j < 8; ++j) s += red[j];
    npt[oct] = s;
  }
}

// ---------- K4: deterministic final reduction ----------
__global__ __launch_bounds__(512) void k_final(
    const float* __restrict__ mu, const int* __restrict__ Tp,
    const float* __restrict__ compP, int nc,
    const float* __restrict__ npt, int nn,
    float* __restrict__ out, int N)
{
  const int tid = threadIdx.x;
  double sc = 0.0, sn = 0.0;
  for (int i = tid; i < nc; i += 512) sc += (double)compP[i];
  for (int i = tid; i < nn; i += 512) sn += (double)npt[i];
  double sm = (tid < MT) ? (double)mu[tid] : 0.0;
  sc = wredd(sc); sn = wredd(sn); sm = wredd(sm);
  __shared__ double s3[3][8];
  const int wv = tid >> 6, lane = tid & 63;
  if (lane == 0) { s3[0][wv]=sc; s3[1][wv]=sn; s3[2][wv]=sm; }
  __syncthreads();
  if (tid == 0) {
    double C=0.0, L=0.0, Mm=0.0;
    #pragma unroll
    for (int j = 0; j < 8; ++j) { C+=s3[0][j]; L+=s3[1][j]; Mm+=s3[2][j]; }
    L *= 0.6931471805599453;             // acc was log2
    double T = (double)parse_T(Tp);
    out[0] = (float)((C + T*Mm - L) / (double)N);
  }
}

extern "C" void kernel_launch(void* const* d_in, const int* in_sizes, int n_in,
                              void* d_out, int out_size, void* d_ws, size_t ws_size,
                              hipStream_t stream)
{
  const float* mu    = (const float*)d_in[0];
  const float* alpha = (const float*)d_in[1];   // (K, M, M)
  const float* gamma = (const float*)d_in[2];   // (K,)
  const float* t     = (const float*)d_in[3];   // (N,)
  const int*   mi    = (const int*)d_in[4];     // (N,) int32
  const int*   Tp    = (const int*)d_in[5];     // scalar
  const int N = in_sizes[3];
  const int B   = (N + NBK - 1) / NBK;          // 49 at N=200k
  const int NOG = NBK / 8;                      // 512 WGs / octets

  float* p = (float*)d_ws;
  float4* cd4G  = (float4*)p; p += (size_t)N*4;
  float*  slG   = p;          p += ((size_t)N + 3) & ~(size_t)3;
  float4* Cl8   = (float4*)p; p += (size_t)NBK*256;
  float4* Dc8   = (float4*)p; p += (size_t)NBK*4;
  float4* Ag    = (float4*)p; p += (size_t)NOG*256;
  float4* gdec  = (float4*)p; p += (size_t)NOG*4;
  float4* SgG   = (float4*)p; p += (size_t)16*256;
  float4* sdecG = (float4*)p; p += (size_t)16*4;
  float*  compP = p;          p += NOG;
  float*  npt   = p;          p += NOG;

  k_phase1<<<NOG, 512, 0, stream>>>(t, mi, alpha, gamma, Tp, cd4G, slG,
                                    Cl8, Dc8, Ag, gdec, compP, N, B);
  k_scan2 <<<16,  64,  0, stream>>>(Ag, gdec, SgG, sdecG);
  k_lam   <<<NOG, 512, 0, stream>>>(mi, mu, cd4G, slG, Cl8, Dc8, Ag, gdec,
                                    SgG, sdecG, npt, N, B);
  k_final <<<1,   512, 0, stream>>>(mu, Tp, compP, NOG, npt, NOG,
                                    (float*)d_out, N);
}